// Round 4
// baseline (390.078 us; speedup 1.0000x reference)
//
#include <hip/hip_runtime.h>
#include <cmath>

#define EPSF 1e-5f

// ---------------------------------------------------------------------------
// ws float layout:
//   W2F  = ws        : float4[15][7][45]  folded stage-2 conv weights (expert innermost)
//   FC2  = +19576    : float4[2][15][45]  fcw2 re-laid (expert innermost)
//   IMG  = +25088    : float [4096]       table image (copied to LDS by fused_k):
//       [0,240)    W1P   [20][12] folded stage-1 conv w (row pad 9->12)
//       [240,2400) FCW1R [20][9][12] fcw1 re-laid [ch][pp][class pad 10->12]
//       [2400,2420) B1F  [20] folded stage-1 bias
//       [2420,2432) FCB1 [10] (+2 pad)
//       [2432,3108) B2F  [15][45] folded stage-2 bias (+1 pad)
//       [3108,4096) FCB2 [2][45] (+pad)
// total 29184 floats (~117 KB)
// ---------------------------------------------------------------------------
#define OFF_FC2   19576
#define OFF_IMG   25088

#define I_W1P    0
#define I_FCW1R  240
#define I_B1F    2400
#define I_FCB1   2420
#define I_B2F    2432
#define I_FCB2   3108

__global__ __launch_bounds__(256) void setup_tables(
    const float* __restrict__ w1, const float* __restrict__ b1,
    const float* __restrict__ g1, const float* __restrict__ be1,
    const float* __restrict__ m1, const float* __restrict__ v1,
    const float* __restrict__ w2, const float* __restrict__ b2,
    const float* __restrict__ g2, const float* __restrict__ be2,
    const float* __restrict__ m2, const float* __restrict__ v2,
    const float* __restrict__ fcw2, const float* __restrict__ fcb2,
    const float* __restrict__ fcw1, const float* __restrict__ fcb1,
    float* __restrict__ ws)
{
  const int t  = blockIdx.x * blockDim.x + threadIdx.x;
  const int nt = gridDim.x * blockDim.x;
  float* W2F = ws;
  float* FC2 = ws + OFF_FC2;
  float* IMG = ws + OFF_IMG;

  for (int idx = t; idx < 18900; idx += nt) {
    int kk = idx & 3, rest = idx >> 2;
    int e = rest % 45, ok4 = rest / 45;
    int k4 = ok4 % 7, o = ok4 / 7;
    int k = k4 * 4 + kk;
    float s = g2[e*15+o] / sqrtf(v2[e*15+o] + EPSF);
    W2F[idx] = (k < 25) ? w2[(e*15+o)*25 + k] * s : 0.0f;
  }
  for (int idx = t; idx < 5400; idx += nt) {
    int kk = idx & 3, rest = idx >> 2;
    int e = rest % 45, t2 = rest / 45;
    int f4 = t2 % 15, oo = t2 / 15;
    FC2[idx] = fcw2[(e*2+oo)*60 + f4*4 + kk];
  }
  for (int i = t; i < 4096; i += nt) {
    float v = 0.0f;
    if (i < I_FCW1R) {
      int ch = i / 12, j = i % 12;
      if (j < 9) {
        float s = g1[ch] / sqrtf(v1[ch] + EPSF);
        v = w1[ch*9 + j] * s;
      }
    } else if (i < I_B1F) {
      int k = i - I_FCW1R;
      int c = k % 12, r2 = k / 12, pp = r2 % 9, ch = r2 / 9;
      if (c < 10) v = fcw1[c*180 + ch*9 + pp];
    } else if (i < I_FCB1) {
      int ch = i - I_B1F;
      float s = g1[ch] / sqrtf(v1[ch] + EPSF);
      v = b1[ch]*s + be1[ch] - m1[ch]*s;
    } else if (i < I_B2F) {
      int k = i - I_FCB1;
      if (k < 10) v = fcb1[k];
    } else if (i < I_FCB2) {
      int k = i - I_B2F;
      if (k < 675) {
        int e = k % 45, o = k / 45;
        float s = g2[e*15+o] / sqrtf(v2[e*15+o] + EPSF);
        v = b2[e*15+o]*s + be2[e*15+o] - m2[e*15+o]*s;
      }
    } else {
      int k = i - I_FCB2;
      if (k < 90) {
        int e = k % 45, oo = k / 45;
        v = fcb2[e*2+oo];
      }
    }
    IMG[i] = v;
  }
}

#define GETC(arr, k) ((k)%4==0 ? arr[(k)/4].x : (k)%4==1 ? arr[(k)/4].y : \
                      (k)%4==2 ? arr[(k)/4].z : arr[(k)/4].w)

// ---------------------------------------------------------------------------
// 4 threads per sample.  LDS (floats), total 9760 = 39 KB -> 4 blocks/CU:
//   [0,4352)      xds: 64 samples x 68-stride (8x8 tile at sl*68)
//                 -- reused after stage 1: [0,640) out1, [640,1280) out2
//   [4352,9760)   RAW: 8-sample chunk staging (stride 676)
//                 -- reused after staging: TAB = 4096-float table image
//                    (stage-1 weights + biases; RAW is dead once the chunk
//                    loop's final barrier retires, so TAB overlays it)
//
// Round-3 post-mortem fixes:
//   * amdgpu_waves_per_eu(4,4): occupancy is LDS/grid-capped at 4 waves/EU,
//     so pin the allocator to the matching 128-VGPR budget.  With (2,4) it
//     chose 64 VGPRs and rematerialized xd[64] from LDS inside the conv
//     loops (the 131 us, 1.2M-bank-conflict regression).
//   * stage-1 tables back in LDS (TAB) -- reading them through L1 put ~150
//     multi-address vector-mem instructions/thread on the TA pipe (~15 us/CU).
//     Only the big eid-gathered W2F/FC2 (96 KB) stay in L2.
// ---------------------------------------------------------------------------
#define T_RAW   4352
#define T_TAB   4352
#define SSTR    676      // raw per-sample stride in floats (676 % 32 = 4)

__global__ __attribute__((amdgpu_waves_per_eu(4, 4))) __launch_bounds__(256)
void fused_k(
    const float* __restrict__ x,
    const float* __restrict__ ws,
    float* __restrict__ out, int B)
{
  __shared__ float lds[9760];

  const int t  = threadIdx.x;
  const int p  = t & 3;            // part 0..3
  const int sl = t >> 2;           // sample slot 0..63
  const int b  = blockIdx.x * 64 + sl;
  const bool valid = (b < B);

  // ---- issue table-image loads first (L2-resident, long latency budget) ----
  const float4* img4 = reinterpret_cast<const float4*>(ws + OFF_IMG);
  float4 tv0 = img4[t], tv1 = img4[t + 256], tv2 = img4[t + 512], tv3 = img4[t + 768];

  // ---- staging thread mapping ----
  const int s8  = t >> 5;          // sample-in-chunk 0..7 (load phase)
  const int tin = t & 31;          // 0..31, loads float4 tin+32j

  // ---- prologue: load chunk 0 ----
  float4 pre[6];
  {
    const int bs = blockIdx.x * 64 + s8;
    if (bs < B) {
      const float4* xp = reinterpret_cast<const float4*>(x + (size_t)bs * 784);
      #pragma unroll
      for (int j = 0; j < 5; j++) pre[j] = xp[tin + 32*j];
      pre[5] = (tin < 8) ? xp[tin + 160] : make_float4(0.f,0.f,0.f,0.f);
    } else {
      #pragma unroll
      for (int j = 0; j < 6; j++) pre[j] = make_float4(0.f,0.f,0.f,0.f);
    }
    float4* rw = reinterpret_cast<float4*>(&lds[T_RAW + s8*SSTR]);
    #pragma unroll
    for (int j = 0; j < 5; j++) rw[tin + 32*j] = pre[j];
    if (tin < 8) rw[tin + 160] = pre[5];
  }
  __syncthreads();

  // ---- 8 chunks: prefetch c+1 || downscale c ----
  #pragma unroll 1
  for (int c = 0; c < 8; c++) {
    if (c < 7) {                       // issue next chunk's loads early
      const int bs = blockIdx.x * 64 + (c+1)*8 + s8;
      if (bs < B) {
        const float4* xp = reinterpret_cast<const float4*>(x + (size_t)bs * 784);
        #pragma unroll
        for (int j = 0; j < 5; j++) pre[j] = xp[tin + 32*j];
        pre[5] = (tin < 8) ? xp[tin + 160] : make_float4(0.f,0.f,0.f,0.f);
      }
    }
    // downscale chunk c: thread (ds8, orow, h) -> xd[orow][4h..4h+3]
    if (t < 128) {
      const int ds8  = t >> 4;
      const int orow = (t >> 1) & 7;
      const int h    = t & 1;
      float a0 = 0.f, a1 = 0.f, a2 = 0.f, a3 = 0.f;
      #pragma unroll
      for (int dr = 0; dr < 3; dr++) {
        const float4* rp = reinterpret_cast<const float4*>(
            &lds[T_RAW + ds8*SSTR + (3*orow + dr)*28 + 12*h]);
        float4 q0 = rp[0], q1 = rp[1], q2 = rp[2];
        a0 += q0.x + q0.y + q0.z;
        a1 += q0.w + q1.x + q1.y;
        a2 += q1.z + q1.w + q2.x;
        a3 += q2.y + q2.z + q2.w;
      }
      float4* dst = reinterpret_cast<float4*>(&lds[(c*8 + ds8)*68 + orow*8 + 4*h]);
      *dst = make_float4(a0*(1.f/9.f), a1*(1.f/9.f), a2*(1.f/9.f), a3*(1.f/9.f));
    }
    __syncthreads();                   // raw(c) reads done; xds(c) visible
    if (c < 7) {
      float4* rw = reinterpret_cast<float4*>(&lds[T_RAW + s8*SSTR]);
      #pragma unroll
      for (int j = 0; j < 5; j++) rw[tin + 32*j] = pre[j];
      if (tin < 8) rw[tin + 160] = pre[5];
      __syncthreads();                 // raw(c+1) visible
    }
  }

  // ---- RAW is dead; overlay TAB (table image) on it ----
  {
    float4* tab4 = reinterpret_cast<float4*>(&lds[T_TAB]);
    tab4[t] = tv0; tab4[t + 256] = tv1; tab4[t + 512] = tv2; tab4[t + 768] = tv3;
  }

  // ---- every part reads its sample's full 8x8 tile into registers ----
  float xd[64];
  #pragma unroll
  for (int r = 0; r < 8; r++) {
    const float4* src = reinterpret_cast<const float4*>(&lds[sl*68 + r*8]);
    float4 a = src[0], bq = src[1];
    xd[r*8+0]=a.x;  xd[r*8+1]=a.y;  xd[r*8+2]=a.z;  xd[r*8+3]=a.w;
    xd[r*8+4]=bq.x; xd[r*8+5]=bq.y; xd[r*8+6]=bq.z; xd[r*8+7]=bq.w;
  }
  __syncthreads();                     // TAB visible

  // ---- stage 1: 5 channels per part (weights from LDS TAB) ----
  float logits[10];
  #pragma unroll
  for (int c = 0; c < 10; c++) logits[c] = 0.0f;

  #pragma unroll 1
  for (int ci = 0; ci < 5; ci++) {
    const int ch = p*5 + ci;
    const float4* wp = reinterpret_cast<const float4*>(&lds[T_TAB + I_W1P + ch*12]);
    float4 w0 = wp[0], w1v = wp[1], w2v = wp[2];
    const float w_[9] = {w0.x,w0.y,w0.z,w0.w,w1v.x,w1v.y,w1v.z,w1v.w,w2v.x};
    const float bb = lds[T_TAB + I_B1F + ch];
    float feat[9];
    #pragma unroll
    for (int pr = 0; pr < 3; pr++) {
      #pragma unroll
      for (int pc = 0; pc < 3; pc++) {
        float c00 = bb, c01 = bb, c10 = bb, c11 = bb;
        #pragma unroll
        for (int dr = 0; dr < 3; dr++) {
          #pragma unroll
          for (int dc = 0; dc < 3; dc++) {
            float wk = w_[dr*3 + dc];
            c00 = fmaf(xd[(2*pr+0+dr)*8 + 2*pc+0+dc], wk, c00);
            c01 = fmaf(xd[(2*pr+0+dr)*8 + 2*pc+1+dc], wk, c01);
            c10 = fmaf(xd[(2*pr+1+dr)*8 + 2*pc+0+dc], wk, c10);
            c11 = fmaf(xd[(2*pr+1+dr)*8 + 2*pc+1+dc], wk, c11);
          }
        }
        feat[pr*3+pc] = fmaxf(fmaxf(fmaxf(c00, c01), fmaxf(c10, c11)), 0.0f);
      }
    }
    #pragma unroll
    for (int pp = 0; pp < 9; pp++) {
      const float4* f4 = reinterpret_cast<const float4*>(&lds[T_TAB + I_FCW1R + (ch*9 + pp)*12]);
      float4 f0 = f4[0], f1 = f4[1], f2 = f4[2];
      const float fv = feat[pp];
      logits[0] = fmaf(fv, f0.x, logits[0]);
      logits[1] = fmaf(fv, f0.y, logits[1]);
      logits[2] = fmaf(fv, f0.z, logits[2]);
      logits[3] = fmaf(fv, f0.w, logits[3]);
      logits[4] = fmaf(fv, f1.x, logits[4]);
      logits[5] = fmaf(fv, f1.y, logits[5]);
      logits[6] = fmaf(fv, f1.z, logits[6]);
      logits[7] = fmaf(fv, f1.w, logits[7]);
      logits[8] = fmaf(fv, f2.x, logits[8]);
      logits[9] = fmaf(fv, f2.y, logits[9]);
    }
  }

  // butterfly all-reduce over the 4 parts, + bias
  #pragma unroll
  for (int c = 0; c < 10; c++) {
    float v = logits[c];
    v += __shfl_xor(v, 1);
    v += __shfl_xor(v, 2);
    logits[c] = v + lds[T_TAB + I_FCB1 + c];
  }

  // ---- top-2 (stable-argsort tie semantics) ----
  int i1 = 0; float v1m = logits[0];
  #pragma unroll
  for (int c = 1; c < 10; c++) { if (logits[c] >= v1m) { v1m = logits[c]; i1 = c; } }
  int i2 = 0; float v2m = -3.0e38f;
  #pragma unroll
  for (int c = 0; c < 10; c++) { if (c != i1 && logits[c] >= v2m) { v2m = logits[c]; i2 = c; } }
  const int idx0 = i1 < i2 ? i1 : i2;
  const int idx1 = i1 < i2 ? i2 : i1;
  int eid = 8*idx0 - (idx0*(idx0-1))/2 + idx1 - 1;
  eid = eid < 0 ? 0 : (eid > 44 ? 44 : eid);

  float sume = 0.0f;
  #pragma unroll
  for (int c = 0; c < 10; c++) sume += __expf(logits[c] - v1m);
  const bool use1 = (-__logf(sume)) > 0.3f;

  // ---- stash logits (= out1) in LDS ----
  __syncthreads();                       // all reads of xds region done
  if (p == 0) {
    #pragma unroll
    for (int c = 0; c < 5; c++) lds[sl*10 + c] = logits[c];
  } else if (p == 1) {
    #pragma unroll
    for (int c = 5; c < 10; c++) lds[sl*10 + c] = logits[c];
  }

  // ---- stage 2: channels o = p + 4*oi (weights gathered from L2) ----
  const float4* W2F4 = reinterpret_cast<const float4*>(ws);
  const float4* FC24 = reinterpret_cast<const float4*>(ws + OFF_FC2);
  float s2a = 0.0f, s2b = 0.0f;

  #pragma unroll 1
  for (int oi = 0; oi < 4; oi++) {
    const int o = p + 4*oi;
    if (o < 15) {
      float4 wv[7];
      #pragma unroll
      for (int k4 = 0; k4 < 7; k4++) wv[k4] = W2F4[(o*7 + k4)*45 + eid];
      const float bias = lds[T_TAB + I_B2F + o*45 + eid];
      const float4 fa = FC24[o*45 + eid];
      const float4 fb = FC24[(15 + o)*45 + eid];
      float feat0 = 0.f, feat1 = 0.f, feat2 = 0.f, feat3 = 0.f;
      #pragma unroll
      for (int ph = 0; ph < 2; ph++) {
        #pragma unroll
        for (int pw = 0; pw < 2; pw++) {
          float c00 = bias, c01 = bias, c10 = bias, c11 = bias;
          #pragma unroll
          for (int i = 0; i < 5; i++) {
            #pragma unroll
            for (int j = 0; j < 5; j++) {
              float wk = GETC(wv, i*5 + j);
              c00 = fmaf(xd[(2*ph+0+i)*8 + 2*pw+0+j], wk, c00);
              c01 = fmaf(xd[(2*ph+0+i)*8 + 2*pw+1+j], wk, c01);
              c10 = fmaf(xd[(2*ph+1+i)*8 + 2*pw+0+j], wk, c10);
              c11 = fmaf(xd[(2*ph+1+i)*8 + 2*pw+1+j], wk, c11);
            }
          }
          float f = fmaxf(fmaxf(fmaxf(c00, c01), fmaxf(c10, c11)), 0.0f);
          if (ph == 0 && pw == 0) feat0 = f;
          else if (ph == 0)       feat1 = f;
          else if (pw == 0)       feat2 = f;
          else                    feat3 = f;
        }
      }
      s2a = fmaf(feat0, fa.x, fmaf(feat1, fa.y, fmaf(feat2, fa.z, fmaf(feat3, fa.w, s2a))));
      s2b = fmaf(feat0, fb.x, fmaf(feat1, fb.y, fmaf(feat2, fb.z, fmaf(feat3, fb.w, s2b))));
    }
  }
  s2a += __shfl_xor(s2a, 1); s2a += __shfl_xor(s2a, 2);
  s2b += __shfl_xor(s2b, 1); s2b += __shfl_xor(s2b, 2);
  s2a += lds[T_TAB + I_FCB2 + eid];
  s2b += lds[T_TAB + I_FCB2 + 45 + eid];

  // ---- scatter + log_softmax (logits from LDS) ----
  __syncthreads();
  float o10[10];
  #pragma unroll
  for (int c = 0; c < 10; c++) {
    float v = -100.0f;
    v = (c == idx0) ? s2a : v;
    v = (c == idx1) ? s2b : v;
    o10[c] = use1 ? lds[sl*10 + c] : v;
  }
  float m2x = o10[0];
  #pragma unroll
  for (int c = 1; c < 10; c++) m2x = fmaxf(m2x, o10[c]);
  float se2 = 0.0f;
  #pragma unroll
  for (int c = 0; c < 10; c++) se2 += __expf(o10[c] - m2x);
  const float lse2 = m2x + __logf(se2);

  // ---- stage out2 into LDS; coalesced float4 block store ----
  if (p == 2) {
    #pragma unroll
    for (int c = 0; c < 5; c++) lds[640 + sl*10 + c] = o10[c] - lse2;
  } else if (p == 3) {
    #pragma unroll
    for (int c = 5; c < 10; c++) lds[640 + sl*10 + c] = o10[c] - lse2;
  }
  __syncthreads();

  if (blockIdx.x * 64 + 64 <= B) {
    const float4* l4 = reinterpret_cast<const float4*>(lds);
    const size_t o1 = (size_t)blockIdx.x * 640;
    if (t < 160)
      *reinterpret_cast<float4*>(out + o1 + (size_t)t*4) = l4[t];
    if (t >= 96)
      *reinterpret_cast<float4*>(out + (size_t)B*10 + o1 + (size_t)(t-96)*4) = l4[160 + (t-96)];
  } else if (valid) {
    const size_t base = (size_t)b * 10;
    if (p == 0) {
      #pragma unroll
      for (int c = 0; c < 5; c++) out[base + c] = lds[sl*10 + c];
    } else if (p == 1) {
      #pragma unroll
      for (int c = 5; c < 10; c++) out[base + c] = lds[sl*10 + c];
    } else if (p == 2) {
      #pragma unroll
      for (int c = 0; c < 5; c++) out[(size_t)B*10 + base + c] = lds[640 + sl*10 + c];
    } else {
      #pragma unroll
      for (int c = 5; c < 10; c++) out[(size_t)B*10 + base + c] = lds[640 + sl*10 + c];
    }
  }
}

extern "C" void kernel_launch(void* const* d_in, const int* in_sizes, int n_in,
                              void* d_out, int out_size, void* d_ws, size_t ws_size,
                              hipStream_t stream) {
  const float* x    = (const float*)d_in[0];
  const float* w1   = (const float*)d_in[1];
  const float* b1   = (const float*)d_in[2];
  const float* g1   = (const float*)d_in[3];
  const float* be1  = (const float*)d_in[4];
  const float* m1   = (const float*)d_in[5];
  const float* v1   = (const float*)d_in[6];
  const float* fcw1 = (const float*)d_in[7];
  const float* fcb1 = (const float*)d_in[8];
  const float* w2   = (const float*)d_in[9];
  const float* b2   = (const float*)d_in[10];
  const float* g2   = (const float*)d_in[11];
  const float* be2  = (const float*)d_in[12];
  const float* m2   = (const float*)d_in[13];
  const float* v2   = (const float*)d_in[14];
  const float* fcw2 = (const float*)d_in[15];
  const float* fcb2 = (const float*)d_in[16];
  float* out = (float*)d_out;
  float* ws  = (float*)d_ws;
  const int B = in_sizes[0] / 784;

  setup_tables<<<80, 256, 0, stream>>>(w1, b1, g1, be1, m1, v1,
                                       w2, b2, g2, be2, m2, v2,
                                       fcw2, fcb2, fcw1, fcb1, ws);
  fused_k<<<(B + 63)/64, 256, 0, stream>>>(x, ws, out, B);
}

// Round 5
// 345.528 us; speedup vs baseline: 1.1289x; 1.1289x over previous
//
#include <hip/hip_runtime.h>
#include <cmath>

#define EPSF 1e-5f

// ---------------------------------------------------------------------------
// ws float layout:
//   W2F  = ws        : float4[15][7][45]  folded stage-2 conv weights (expert innermost)
//   FC2P = +19576    : float [2][15][4][45] fcw2 re-laid COMPONENT-major
//                      (pool-position p then expert innermost)
//   IMG  = +25088    : float [4096]       table image (copied to LDS by fused_k):
//       [0,240)    W1P   [20][12] folded stage-1 conv w (row pad 9->12)
//       [240,2400) FCW1R [20][9][12] fcw1 re-laid [ch][pp][class pad 10->12]
//       [2400,2420) B1F  [20] folded stage-1 bias
//       [2420,2432) FCB1 [10] (+2 pad)
//       [2432,3108) B2F  [15][45] folded stage-2 bias (+1 pad)
//       [3108,4096) FCB2 [2][45] (+pad)
// ---------------------------------------------------------------------------
#define OFF_FC2   19576
#define OFF_IMG   25088

#define I_W1P    0
#define I_FCW1R  240
#define I_B1F    2400
#define I_FCB1   2420
#define I_B2F    2432
#define I_FCB2   3108

__global__ __launch_bounds__(256) void setup_tables(
    const float* __restrict__ w1, const float* __restrict__ b1,
    const float* __restrict__ g1, const float* __restrict__ be1,
    const float* __restrict__ m1, const float* __restrict__ v1,
    const float* __restrict__ w2, const float* __restrict__ b2,
    const float* __restrict__ g2, const float* __restrict__ be2,
    const float* __restrict__ m2, const float* __restrict__ v2,
    const float* __restrict__ fcw2, const float* __restrict__ fcb2,
    const float* __restrict__ fcw1, const float* __restrict__ fcb1,
    float* __restrict__ ws)
{
  const int t  = blockIdx.x * blockDim.x + threadIdx.x;
  const int nt = gridDim.x * blockDim.x;
  float* W2F  = ws;
  float* FC2P = ws + OFF_FC2;
  float* IMG  = ws + OFF_IMG;

  for (int idx = t; idx < 18900; idx += nt) {
    int kk = idx & 3, rest = idx >> 2;
    int e = rest % 45, ok4 = rest / 45;
    int k4 = ok4 % 7, o = ok4 / 7;
    int k = k4 * 4 + kk;
    float s = g2[e*15+o] / sqrtf(v2[e*15+o] + EPSF);
    W2F[idx] = (k < 25) ? w2[(e*15+o)*25 + k] * s : 0.0f;
  }
  // FC2P[((oo*15+o)*4+pos)*45 + e] = fcw2[(e*2+oo)*60 + o*4 + pos]
  for (int idx = t; idx < 5400; idx += nt) {
    int e = idx % 45, r = idx / 45;
    int pos = r % 4, r2 = r / 4;
    int o = r2 % 15, oo = r2 / 15;
    FC2P[idx] = fcw2[(e*2+oo)*60 + o*4 + pos];
  }
  for (int i = t; i < 4096; i += nt) {
    float v = 0.0f;
    if (i < I_FCW1R) {
      int ch = i / 12, j = i % 12;
      if (j < 9) {
        float s = g1[ch] / sqrtf(v1[ch] + EPSF);
        v = w1[ch*9 + j] * s;
      }
    } else if (i < I_B1F) {
      int k = i - I_FCW1R;
      int c = k % 12, r2 = k / 12, pp = r2 % 9, ch = r2 / 9;
      if (c < 10) v = fcw1[c*180 + ch*9 + pp];
    } else if (i < I_FCB1) {
      int ch = i - I_B1F;
      float s = g1[ch] / sqrtf(v1[ch] + EPSF);
      v = b1[ch]*s + be1[ch] - m1[ch]*s;
    } else if (i < I_B2F) {
      int k = i - I_FCB1;
      if (k < 10) v = fcb1[k];
    } else if (i < I_FCB2) {
      int k = i - I_B2F;
      if (k < 675) {
        int e = k % 45, o = k / 45;
        float s = g2[e*15+o] / sqrtf(v2[e*15+o] + EPSF);
        v = b2[e*15+o]*s + be2[e*15+o] - m2[e*15+o]*s;
      }
    } else {
      int k = i - I_FCB2;
      if (k < 90) {
        int e = k % 45, oo = k / 45;
        v = fcb2[e*2+oo];
      }
    }
    IMG[i] = v;
  }
}

#define GETC(arr, k) ((k)%4==0 ? arr[(k)/4].x : (k)%4==1 ? arr[(k)/4].y : \
                      (k)%4==2 ? arr[(k)/4].z : arr[(k)/4].w)

// ---------------------------------------------------------------------------
// 4 threads per sample, SPATIAL split (round-4 post-mortem: the allocator
// pins this kernel at 64 VGPRs no matter what occupancy attributes say, so
// the kernel is designed to FIT 64 regs: each part holds only a 6x6 = 36
// float quadrant xl, not the 8x8 = 64 tile).
//   part p: region rows R0..R0+5, cols C0..C0+5; R0 = p&2, C0 = (p&1)*2.
//   stage 2: part p computes ALL 15 channels at pool position (p>>1, p&1)
//            -> local conv indices are uniform 0..5 (compile-time).
//            FC2 read component-major (FC2P), butterfly-summed.
//   stage 1: part p computes its local 2x2 pool grid for ALL 20 channels,
//            masked by compile-time ownership (each of the 9 global pool
//            positions owned by exactly one part: masks {3,14,5,12}),
//            feats (masked to 0) feed logits; butterfly sums parts.
// LDS (floats), total 9760 = 39 KB -> 4 blocks/CU:
//   [0,4352)      xds: 64 samples x 68-stride (8x8 tile at sl*68)
//                 -- reused after stage 1: [0,640) out1, [640,1280) out2
//   [4352,9760)   RAW: 8-sample chunk staging (stride 676)
//                 -- reused after staging: TAB = 4096-float table image
//                    (copied AFTER the chunk loop, load->store, 4 transient
//                    regs -- R4's 64-reg-long-lived preload was the spill)
// ---------------------------------------------------------------------------
#define T_RAW   4352
#define T_TAB   4352
#define SSTR    676      // raw per-sample stride in floats

__global__ __launch_bounds__(256) void fused_k(
    const float* __restrict__ x,
    const float* __restrict__ ws,
    float* __restrict__ out, int B)
{
  __shared__ float lds[9760];

  const int t  = threadIdx.x;
  const int p  = t & 3;            // part 0..3
  const int sl = t >> 2;           // sample slot 0..63
  const int b  = blockIdx.x * 64 + sl;
  const bool valid = (b < B);

  // ---- staging thread mapping ----
  const int s8  = t >> 5;          // sample-in-chunk 0..7 (load phase)
  const int tin = t & 31;          // 0..31, loads float4 tin+32j

  // ---- prologue: load chunk 0 (rows 0..23 of x, 168 float4, coalesced) ----
  float4 pre[6];
  {
    const int bs = blockIdx.x * 64 + s8;
    if (bs < B) {
      const float4* xp = reinterpret_cast<const float4*>(x + (size_t)bs * 784);
      #pragma unroll
      for (int j = 0; j < 5; j++) pre[j] = xp[tin + 32*j];
      pre[5] = (tin < 8) ? xp[tin + 160] : make_float4(0.f,0.f,0.f,0.f);
    } else {
      #pragma unroll
      for (int j = 0; j < 6; j++) pre[j] = make_float4(0.f,0.f,0.f,0.f);
    }
    float4* rw = reinterpret_cast<float4*>(&lds[T_RAW + s8*SSTR]);
    #pragma unroll
    for (int j = 0; j < 5; j++) rw[tin + 32*j] = pre[j];
    if (tin < 8) rw[tin + 160] = pre[5];
  }
  __syncthreads();

  // ---- 8 chunks: prefetch c+1 || downscale c ----
  #pragma unroll 1
  for (int c = 0; c < 8; c++) {
    if (c < 7) {
      const int bs = blockIdx.x * 64 + (c+1)*8 + s8;
      if (bs < B) {
        const float4* xp = reinterpret_cast<const float4*>(x + (size_t)bs * 784);
        #pragma unroll
        for (int j = 0; j < 5; j++) pre[j] = xp[tin + 32*j];
        pre[5] = (tin < 8) ? xp[tin + 160] : make_float4(0.f,0.f,0.f,0.f);
      }
    }
    if (t < 128) {
      const int ds8  = t >> 4;
      const int orow = (t >> 1) & 7;
      const int h    = t & 1;
      float a0 = 0.f, a1 = 0.f, a2 = 0.f, a3 = 0.f;
      #pragma unroll
      for (int dr = 0; dr < 3; dr++) {
        const float4* rp = reinterpret_cast<const float4*>(
            &lds[T_RAW + ds8*SSTR + (3*orow + dr)*28 + 12*h]);
        float4 q0 = rp[0], q1 = rp[1], q2 = rp[2];
        a0 += q0.x + q0.y + q0.z;
        a1 += q0.w + q1.x + q1.y;
        a2 += q1.z + q1.w + q2.x;
        a3 += q2.y + q2.z + q2.w;
      }
      float4* dst = reinterpret_cast<float4*>(&lds[(c*8 + ds8)*68 + orow*8 + 4*h]);
      *dst = make_float4(a0*(1.f/9.f), a1*(1.f/9.f), a2*(1.f/9.f), a3*(1.f/9.f));
    }
    __syncthreads();                   // raw(c) reads done; xds(c) visible
    if (c < 7) {
      float4* rw = reinterpret_cast<float4*>(&lds[T_RAW + s8*SSTR]);
      #pragma unroll
      for (int j = 0; j < 5; j++) rw[tin + 32*j] = pre[j];
      if (tin < 8) rw[tin + 160] = pre[5];
      __syncthreads();                 // raw(c+1) visible
    }
  }

  // ---- issue TAB image loads (L2-resident), read xl, then store TAB ----
  const float4* img4 = reinterpret_cast<const float4*>(ws + OFF_IMG);
  float4 tv0 = img4[t];
  float4 tv1 = img4[t + 256];
  float4 tv2 = img4[t + 512];
  float4 tv3 = img4[t + 768];

  // part's 6x6 quadrant into registers (float2 reads, 8B aligned)
  const int R0 = p & 2;
  const int C0 = (p & 1) * 2;
  float xl[36];
  #pragma unroll
  for (int lr = 0; lr < 6; lr++) {
    const float2* src = reinterpret_cast<const float2*>(&lds[sl*68 + (R0+lr)*8 + C0]);
    float2 q0 = src[0], q1 = src[1], q2 = src[2];
    xl[lr*6+0]=q0.x; xl[lr*6+1]=q0.y; xl[lr*6+2]=q1.x;
    xl[lr*6+3]=q1.y; xl[lr*6+4]=q2.x; xl[lr*6+5]=q2.y;
  }
  {
    float4* tab4 = reinterpret_cast<float4*>(&lds[T_TAB]);
    tab4[t] = tv0; tab4[t + 256] = tv1; tab4[t + 512] = tv2; tab4[t + 768] = tv3;
  }
  __syncthreads();                     // TAB visible

  // ---- stage 1: all 20 channels, local 2x2 pool grid, ownership-masked ----
  const int basegpp = (p >> 1) * 3 + (p & 1);   // global pp of local (0,0)
  float logits[10];
  #pragma unroll
  for (int c = 0; c < 10; c++) logits[c] = 0.0f;

  #pragma unroll 1
  for (int ch = 0; ch < 20; ch++) {
    const float4* wp = reinterpret_cast<const float4*>(&lds[T_TAB + I_W1P + ch*12]);
    float4 w0 = wp[0], w1v = wp[1], w2v = wp[2];
    const float w_[9] = {w0.x,w0.y,w0.z,w0.w,w1v.x,w1v.y,w1v.z,w1v.w,w2v.x};
    const float bb = lds[T_TAB + I_B1F + ch];
    #pragma unroll
    for (int lp = 0; lp < 4; lp++) {
      const int lpr = lp >> 1, lpc = lp & 1;
      float c00 = bb, c01 = bb, c10 = bb, c11 = bb;
      #pragma unroll
      for (int dr = 0; dr < 3; dr++) {
        #pragma unroll
        for (int dc = 0; dc < 3; dc++) {
          const float wk = w_[dr*3 + dc];
          c00 = fmaf(xl[(2*lpr+0+dr)*6 + 2*lpc+0+dc], wk, c00);
          c01 = fmaf(xl[(2*lpr+0+dr)*6 + 2*lpc+1+dc], wk, c01);
          c10 = fmaf(xl[(2*lpr+1+dr)*6 + 2*lpc+0+dc], wk, c10);
          c11 = fmaf(xl[(2*lpr+1+dr)*6 + 2*lpc+1+dc], wk, c11);
        }
      }
      float f = fmaxf(fmaxf(fmaxf(c00, c01), fmaxf(c10, c11)), 0.0f);
      // ownership of this local position by part (compile-time mask)
      const int MASKS[4] = {3, 14, 5, 12};
      const float fm = ((MASKS[lp] >> p) & 1) ? f : 0.0f;
      const int off = (lp >> 1) * 3 + (lp & 1);           // 0,1,3,4
      const float4* f4 = reinterpret_cast<const float4*>(
          &lds[T_TAB + I_FCW1R + (ch*9 + basegpp + off)*12]);
      float4 f0 = f4[0], f1 = f4[1], f2 = f4[2];
      logits[0] = fmaf(fm, f0.x, logits[0]);
      logits[1] = fmaf(fm, f0.y, logits[1]);
      logits[2] = fmaf(fm, f0.z, logits[2]);
      logits[3] = fmaf(fm, f0.w, logits[3]);
      logits[4] = fmaf(fm, f1.x, logits[4]);
      logits[5] = fmaf(fm, f1.y, logits[5]);
      logits[6] = fmaf(fm, f1.z, logits[6]);
      logits[7] = fmaf(fm, f1.w, logits[7]);
      logits[8] = fmaf(fm, f2.x, logits[8]);
      logits[9] = fmaf(fm, f2.y, logits[9]);
    }
  }

  // butterfly all-reduce over the 4 parts (bit-identical on all lanes), + bias
  #pragma unroll
  for (int c = 0; c < 10; c++) {
    float v = logits[c];
    v += __shfl_xor(v, 1);
    v += __shfl_xor(v, 2);
    logits[c] = v + lds[T_TAB + I_FCB1 + c];
  }

  // ---- top-2 (stable-argsort tie semantics) ----
  int i1 = 0; float v1m = logits[0];
  #pragma unroll
  for (int c = 1; c < 10; c++) { if (logits[c] >= v1m) { v1m = logits[c]; i1 = c; } }
  int i2 = 0; float v2m = -3.0e38f;
  #pragma unroll
  for (int c = 0; c < 10; c++) { if (c != i1 && logits[c] >= v2m) { v2m = logits[c]; i2 = c; } }
  const int idx0 = i1 < i2 ? i1 : i2;
  const int idx1 = i1 < i2 ? i2 : i1;
  int eid = 8*idx0 - (idx0*(idx0-1))/2 + idx1 - 1;
  eid = eid < 0 ? 0 : (eid > 44 ? 44 : eid);

  float sume = 0.0f;
  #pragma unroll
  for (int c = 0; c < 10; c++) sume += __expf(logits[c] - v1m);
  const bool use1 = (-__logf(sume)) > 0.3f;

  // ---- stash logits (= out1) in LDS; frees them across stage 2 ----
  __syncthreads();                       // all reads of xds region done
  if (p == 0) {
    #pragma unroll
    for (int c = 0; c < 5; c++) lds[sl*10 + c] = logits[c];
  } else if (p == 1) {
    #pragma unroll
    for (int c = 5; c < 10; c++) lds[sl*10 + c] = logits[c];
  }

  // ---- stage 2: ALL 15 channels at this part's pool position p ----
  const float4* W2F4 = reinterpret_cast<const float4*>(ws);
  const float*  FC2P = ws + OFF_FC2;
  float s2a = 0.0f, s2b = 0.0f;

  #pragma unroll 1
  for (int o = 0; o < 15; o++) {
    float4 wv[7];
    #pragma unroll
    for (int k4 = 0; k4 < 7; k4++) wv[k4] = W2F4[(o*7 + k4)*45 + eid];
    const float bias = lds[T_TAB + I_B2F + o*45 + eid];
    const float fa = FC2P[(o*4 + p)*45 + eid];
    const float fb = FC2P[((15 + o)*4 + p)*45 + eid];
    float c00 = bias, c01 = bias, c10 = bias, c11 = bias;
    #pragma unroll
    for (int i = 0; i < 5; i++) {
      #pragma unroll
      for (int j = 0; j < 5; j++) {
        const float wk = GETC(wv, i*5 + j);
        c00 = fmaf(xl[(0+i)*6 + 0+j], wk, c00);
        c01 = fmaf(xl[(0+i)*6 + 1+j], wk, c01);
        c10 = fmaf(xl[(1+i)*6 + 0+j], wk, c10);
        c11 = fmaf(xl[(1+i)*6 + 1+j], wk, c11);
      }
    }
    const float f = fmaxf(fmaxf(fmaxf(c00, c01), fmaxf(c10, c11)), 0.0f);
    s2a = fmaf(f, fa, s2a);
    s2b = fmaf(f, fb, s2b);
  }
  s2a += __shfl_xor(s2a, 1); s2a += __shfl_xor(s2a, 2);
  s2b += __shfl_xor(s2b, 1); s2b += __shfl_xor(s2b, 2);
  s2a += lds[T_TAB + I_FCB2 + eid];
  s2b += lds[T_TAB + I_FCB2 + 45 + eid];

  // ---- scatter + log_softmax (logits from LDS) ----
  __syncthreads();
  float o10[10];
  #pragma unroll
  for (int c = 0; c < 10; c++) {
    float v = -100.0f;
    v = (c == idx0) ? s2a : v;
    v = (c == idx1) ? s2b : v;
    o10[c] = use1 ? lds[sl*10 + c] : v;
  }
  float m2x = o10[0];
  #pragma unroll
  for (int c = 1; c < 10; c++) m2x = fmaxf(m2x, o10[c]);
  float se2 = 0.0f;
  #pragma unroll
  for (int c = 0; c < 10; c++) se2 += __expf(o10[c] - m2x);
  const float lse2 = m2x + __logf(se2);

  // ---- stage out2 into LDS; coalesced float4 block store ----
  if (p == 2) {
    #pragma unroll
    for (int c = 0; c < 5; c++) lds[640 + sl*10 + c] = o10[c] - lse2;
  } else if (p == 3) {
    #pragma unroll
    for (int c = 5; c < 10; c++) lds[640 + sl*10 + c] = o10[c] - lse2;
  }
  __syncthreads();

  if (blockIdx.x * 64 + 64 <= B) {
    const float4* l4 = reinterpret_cast<const float4*>(lds);
    const size_t o1 = (size_t)blockIdx.x * 640;
    if (t < 160)
      *reinterpret_cast<float4*>(out + o1 + (size_t)t*4) = l4[t];
    if (t >= 96)
      *reinterpret_cast<float4*>(out + (size_t)B*10 + o1 + (size_t)(t-96)*4) = l4[160 + (t-96)];
  } else if (valid) {
    const size_t base = (size_t)b * 10;
    if (p == 0) {
      #pragma unroll
      for (int c = 0; c < 5; c++) out[base + c] = lds[sl*10 + c];
    } else if (p == 1) {
      #pragma unroll
      for (int c = 5; c < 10; c++) out[base + c] = lds[sl*10 + c];
    } else if (p == 2) {
      #pragma unroll
      for (int c = 0; c < 5; c++) out[(size_t)B*10 + base + c] = lds[640 + sl*10 + c];
    } else {
      #pragma unroll
      for (int c = 5; c < 10; c++) out[(size_t)B*10 + base + c] = lds[640 + sl*10 + c];
    }
  }
}

extern "C" void kernel_launch(void* const* d_in, const int* in_sizes, int n_in,
                              void* d_out, int out_size, void* d_ws, size_t ws_size,
                              hipStream_t stream) {
  const float* x    = (const float*)d_in[0];
  const float* w1   = (const float*)d_in[1];
  const float* b1   = (const float*)d_in[2];
  const float* g1   = (const float*)d_in[3];
  const float* be1  = (const float*)d_in[4];
  const float* m1   = (const float*)d_in[5];
  const float* v1   = (const float*)d_in[6];
  const float* fcw1 = (const float*)d_in[7];
  const float* fcb1 = (const float*)d_in[8];
  const float* w2   = (const float*)d_in[9];
  const float* b2   = (const float*)d_in[10];
  const float* g2   = (const float*)d_in[11];
  const float* be2  = (const float*)d_in[12];
  const float* m2   = (const float*)d_in[13];
  const float* v2   = (const float*)d_in[14];
  const float* fcw2 = (const float*)d_in[15];
  const float* fcb2 = (const float*)d_in[16];
  float* out = (float*)d_out;
  float* ws  = (float*)d_ws;
  const int B = in_sizes[0] / 784;

  setup_tables<<<80, 256, 0, stream>>>(w1, b1, g1, be1, m1, v1,
                                       w2, b2, g2, be2, m2, v2,
                                       fcw2, fcb2, fcw1, fcb1, ws);
  fused_k<<<(B + 63)/64, 256, 0, stream>>>(x, ws, out, B);
}